// Round 1
// baseline (110.127 us; speedup 1.0000x reference)
//
#include <hip/hip_runtime.h>

// Problem constants
#define HWSZ 65536             // 256*256
#define PLANE (3 * HWSZ)       // one batch's [3,H,W]
#define OUTSTRIDE (8 * PLANE)  // one full output tensor [8,3,256,256]
#define MAGIC 0x13572468       // != 0xAAAAAAAA ws poison

// ---------------------------------------------------------------------------
// Fully fused: MLP (32 blocks' worth of work embedded in a 256-block render
// grid) + render. Gray outputs (o1,o2 = 2/3 of store traffic) depend only on
// phase-A outs[0..1], so they render while fc1/fc2 still run; only o0 waits
// for the full MLP. x is prefetched into registers before any spin.
//
// Flags in ws (poisoned 0xAAAAAAAA each iter, != MAGIC):
//   phase-A done:  fbase[ blk*16 ],        blk = k*8+b  (0..31)
//   fc1 done:      fbase[(64 +blk)*16]
//   fc2 done:      fbase[(128+blk)*16],    blk = c4*8+b2
__global__ __launch_bounds__(512) void k_fused(
    const float* __restrict__ x,
    const float* __restrict__ f, const float* __restrict__ bf,
    const float* __restrict__ pw1, const float* __restrict__ pb1,
    const float* __restrict__ pw2, const float* __restrict__ pb2,
    const float* __restrict__ fw1, const float* __restrict__ fb1,
    const float* __restrict__ fw2, const float* __restrict__ fb2,
    float* __restrict__ ws, float* __restrict__ out) {
  __shared__ float smem[2304];
  __shared__ float2 tab[576];
  const int t = threadIdx.x;
  const int bx = blockIdx.x, b = blockIdx.y;

  float* outs  = ws;          // [4,8,192]
  float* hc    = ws + 12288;  // [8,192]
  float* param = ws + 13824;  // [8,192]
  int* fbase = (int*)(ws + 16384);

  // ---- render prefetch: issue x loads before anything else ----
  const int s4 = bx * 512 + t;
  const float* xb = x + (size_t)b * PLANE;
  float4 vr = ((const float4*)(xb))[s4];
  float4 vg = ((const float4*)(xb + HWSZ))[s4];
  float4 vb = ((const float4*)(xb + 2 * HWSZ))[s4];

  const bool is_mlp = ((bx & 7) == b);  // 4 MLP blocks per batch, all 8 XCDs

  if (is_mlp) {
    const int km = bx >> 3;        // projection index 0..3
    const int blk = km * 8 + b;    // flag-space id 0..31

    // ======== Phase A: proj (km, b) ========
    {
      int q = t % 48, s = t / 48;  // valid for t<384
      float* sf  = smem;           // 512
      float* red = smem + 512;     // 8*192
      float* sh  = smem + 2048;    // 192

      const float* feat = ((km & 1) ? bf : f) + b * 512;
      if (t < 512) sf[t] = feat[t];
      __syncthreads();
      if (t < 384) {  // 512 -> 192
        const float4* w = (const float4*)(pw1 + (size_t)km * (512 * 192));
        float4 acc = {0.f, 0.f, 0.f, 0.f};
        int i0 = s * 64;
        for (int r = 0; r < 4; ++r) {
          float4 wv[16];
#pragma unroll
          for (int j = 0; j < 16; ++j)
            wv[j] = w[(size_t)(i0 + r * 16 + j) * 48 + q];
#pragma unroll
          for (int j = 0; j < 16; ++j) {
            float v = sf[i0 + r * 16 + j];
            acc.x = fmaf(v, wv[j].x, acc.x); acc.y = fmaf(v, wv[j].y, acc.y);
            acc.z = fmaf(v, wv[j].z, acc.z); acc.w = fmaf(v, wv[j].w, acc.w);
          }
        }
        ((float4*)(red + s * 192))[q] = acc;
      }
      __syncthreads();
      if (t < 192) {
        float a = pb1[km * 192 + t];
#pragma unroll
        for (int s2 = 0; s2 < 8; ++s2) a += red[s2 * 192 + t];
        sh[t] = fmaxf(a, 0.f);
      }
      __syncthreads();
      if (t < 384) {  // 192 -> 192
        const float4* w = (const float4*)(pw2 + (size_t)km * (192 * 192));
        float4 acc = {0.f, 0.f, 0.f, 0.f};
        int i0 = s * 24;
        for (int r = 0; r < 2; ++r) {
          float4 wv[12];
#pragma unroll
          for (int j = 0; j < 12; ++j)
            wv[j] = w[(size_t)(i0 + r * 12 + j) * 48 + q];
#pragma unroll
          for (int j = 0; j < 12; ++j) {
            float v = sh[i0 + r * 12 + j];
            acc.x = fmaf(v, wv[j].x, acc.x); acc.y = fmaf(v, wv[j].y, acc.y);
            acc.z = fmaf(v, wv[j].z, acc.z); acc.w = fmaf(v, wv[j].w, acc.w);
          }
        }
        ((float4*)(red + s * 192))[q] = acc;
      }
      __syncthreads();
      if (t < 192) {
        float a = pb2[km * 192 + t];
#pragma unroll
        for (int s2 = 0; s2 < 8; ++s2) a += red[s2 * 192 + t];
        outs[(km * 8 + b) * 192 + t] = a;
      }
      __syncthreads();  // drain stores before fence
      if (t == 0) {
        __threadfence();
        atomicExch(&fbase[blk * 16], MAGIC);
      }
    }

    // ======== Phase B1: fc1 for (b2=b, quarter c4=km) ========
    const int b2 = b, ob2 = km * 48;
    int qb = t % 12, sb = t / 12;  // valid for t<384

    float4 wv1[18];
    if (t < 384) {  // prefetch fw1 slice BEFORE the spin
      const float4* w = (const float4*)fw1;
      int i0 = sb * 18;
#pragma unroll
      for (int j = 0; j < 18; ++j)
        wv1[j] = w[(size_t)(i0 + j) * 48 + (ob2 >> 2) + qb];
    }

    if (t < 4) {
      while (atomicAdd(&fbase[(t * 8 + b2) * 16], 0) != MAGIC)
        __builtin_amdgcn_s_sleep(2);
    }
    __syncthreads();
    if (t == 0) __threadfence();  // acquire
    __syncthreads();

    {
      float* sc  = smem;           // 576
      float* red = smem + 576;     // 32*48
      for (int idx = t; idx < 576; idx += 512) {
        float v;
        if (idx < 192)      v = outs[(0 * 8 + b2) * 192 + idx];
        else if (idx < 384) v = outs[(1 * 8 + b2) * 192 + (idx - 192)];
        else                v = outs[(2 * 8 + b2) * 192 + (idx - 384)] +
                                outs[(3 * 8 + b2) * 192 + (idx - 384)];
        sc[idx] = v;
      }
      __syncthreads();
      if (t < 384) {
        float4 acc = {0.f, 0.f, 0.f, 0.f};
        int i0 = sb * 18;
#pragma unroll
        for (int j = 0; j < 18; ++j) {
          float v = sc[i0 + j];
          acc.x = fmaf(v, wv1[j].x, acc.x); acc.y = fmaf(v, wv1[j].y, acc.y);
          acc.z = fmaf(v, wv1[j].z, acc.z); acc.w = fmaf(v, wv1[j].w, acc.w);
        }
        ((float4*)(red + sb * 48))[qb] = acc;
      }
      __syncthreads();
      if (t < 48) {
        float a = fb1[ob2 + t];
#pragma unroll
        for (int s2 = 0; s2 < 32; ++s2) a += red[s2 * 48 + t];
        hc[b2 * 192 + ob2 + t] = fmaxf(a, 0.f);
      }
      __syncthreads();
      if (t == 0) {
        __threadfence();
        atomicExch(&fbase[(64 + blk) * 16], MAGIC);
      }
    }

    // ======== Phase B2: fc2, same (b2, c4=km) ========
    float4 wv2[6];
    if (t < 384) {  // prefetch fw2 slice BEFORE the spin
      const float4* w = (const float4*)fw2;
      int i0 = sb * 6;
#pragma unroll
      for (int j = 0; j < 6; ++j)
        wv2[j] = w[(size_t)(i0 + j) * 48 + (ob2 >> 2) + qb];
    }

    if (t < 4) {
      while (atomicAdd(&fbase[(64 + t * 8 + b2) * 16], 0) != MAGIC)
        __builtin_amdgcn_s_sleep(2);
    }
    __syncthreads();
    if (t == 0) __threadfence();  // acquire
    __syncthreads();

    {
      float* sh  = smem;           // 192
      float* red = smem + 576;     // 32*48
      if (t < 192) sh[t] = hc[b2 * 192 + t];
      __syncthreads();
      if (t < 384) {
        float4 acc = {0.f, 0.f, 0.f, 0.f};
        int i0 = sb * 6;
#pragma unroll
        for (int j = 0; j < 6; ++j) {
          float v = sh[i0 + j];
          acc.x = fmaf(v, wv2[j].x, acc.x); acc.y = fmaf(v, wv2[j].y, acc.y);
          acc.z = fmaf(v, wv2[j].z, acc.z); acc.w = fmaf(v, wv2[j].w, acc.w);
        }
        ((float4*)(red + sb * 48))[qb] = acc;
      }
      __syncthreads();
      if (t < 48) {
        float a = fb2[ob2 + t];
#pragma unroll
        for (int s2 = 0; s2 < 32; ++s2) a += red[s2 * 48 + t];
        param[b2 * 192 + ob2 + t] = a;
      }
      __syncthreads();  // drain stores before fence
      if (t == 0) {
        __threadfence();
        atomicExch(&fbase[(128 + blk) * 16], MAGIC);
      }
    }
  } else {
    // Pin the x prefetch on the spin-only path: force the loads to have been
    // issued (and landed in VGPRs) before we park in the flag spin.
    asm volatile("" :: "v"(vr.x), "v"(vg.x), "v"(vb.x));
  }

  // ======== Stage G: gray outputs o1,o2 — need only phase-A outs[0..1] ====
  if (t < 2) {
    while (atomicAdd(&fbase[(t * 8 + b) * 16], 0) != MAGIC)
      __builtin_amdgcn_s_sleep(2);
  }
  __syncthreads();
  if (t == 0) __threadfence();  // acquire
  __syncthreads();

  const int wave = t >> 6, lane = t & 63;
  if (wave < 6) {  // build LUTs for curves 3..8 (gray, param_f / param_b)
    int cur = 3 + wave;
    int oi = cur / 3, c = cur - oi * 3;  // oi = 1,2
    const float* src = outs + ((oi - 1) * 8 + b) * 192 + c * 64;
    float p = src[lane];
    float v = p;  // inclusive scan
#pragma unroll
    for (int d = 1; d < 64; d <<= 1) {
      float n = __shfl_up(v, d, 64);
      if (lane >= d) v += n;
    }
    float total = __shfl(v, 63, 64);
    float norm = 64.f / (total + 1e-30f);
    tab[cur * 64 + lane] = make_float2((v - p) * 0.015625f * norm, p * norm);
  }
  __syncthreads();

  auto idx_of = [&](float v, int& kk, float& tt) {
    int k2 = (int)(v * 64.f);
    k2 = k2 < 0 ? 0 : (k2 > 63 ? 63 : k2);
    kk = k2;
    tt = v - (float)k2 * 0.015625f;
  };
  auto evk = [&](int cur, int k2, float tt) -> float {
    float2 e = tab[cur * 64 + k2];
    return fmaf(tt, e.y, e.x);
  };

  float* o0 = out + (size_t)b * PLANE;
  float* o1 = out + OUTSTRIDE + (size_t)b * PLANE;
  float* o2 = out + 2 * OUTSTRIDE + (size_t)b * PLANE;

  {
    float4 gr;
    gr.x = fmaf(0.299f, vr.x, fmaf(0.587f, vg.x, 0.114f * vb.x));
    gr.y = fmaf(0.299f, vr.y, fmaf(0.587f, vg.y, 0.114f * vb.y));
    gr.z = fmaf(0.299f, vr.z, fmaf(0.587f, vg.z, 0.114f * vb.z));
    gr.w = fmaf(0.299f, vr.w, fmaf(0.587f, vg.w, 0.114f * vb.w));

    int kx, ky, kz, kw; float tx, ty, tz, tw;
    idx_of(gr.x, kx, tx); idx_of(gr.y, ky, ty);
    idx_of(gr.z, kz, tz); idx_of(gr.w, kw, tw);
#pragma unroll
    for (int c = 0; c < 3; ++c) {
      float4 r;
      r.x = evk(3 + c, kx, tx); r.y = evk(3 + c, ky, ty);
      r.z = evk(3 + c, kz, tz); r.w = evk(3 + c, kw, tw);
      ((float4*)(o1 + c * HWSZ))[s4] = r;
    }
#pragma unroll
    for (int c = 0; c < 3; ++c) {
      float4 r;
      r.x = evk(6 + c, kx, tx); r.y = evk(6 + c, ky, ty);
      r.z = evk(6 + c, kz, tz); r.w = evk(6 + c, kw, tw);
      ((float4*)(o2 + c * HWSZ))[s4] = r;
    }
  }

  // ======== Stage F: out0 — needs full fc2 param ========
  if (t < 4) {
    while (atomicAdd(&fbase[(128 + t * 8 + b) * 16], 0) != MAGIC)
      __builtin_amdgcn_s_sleep(2);
  }
  __syncthreads();
  if (t == 0) __threadfence();  // acquire
  __syncthreads();

  if (wave < 3) {  // build LUTs for curves 0..2 (full param)
    const float* src = param + b * 192 + wave * 64;
    float p = src[lane];
    float v = p;
#pragma unroll
    for (int d = 1; d < 64; d <<= 1) {
      float n = __shfl_up(v, d, 64);
      if (lane >= d) v += n;
    }
    float total = __shfl(v, 63, 64);
    float norm = 64.f / (total + 1e-30f);
    tab[wave * 64 + lane] = make_float2((v - p) * 0.015625f * norm, p * norm);
  }
  __syncthreads();

  {
    auto ev4 = [&](int cur, float4 v4) -> float4 {
      int k2; float tt; float4 r;
      idx_of(v4.x, k2, tt); r.x = evk(cur, k2, tt);
      idx_of(v4.y, k2, tt); r.y = evk(cur, k2, tt);
      idx_of(v4.z, k2, tt); r.z = evk(cur, k2, tt);
      idx_of(v4.w, k2, tt); r.w = evk(cur, k2, tt);
      return r;
    };
    ((float4*)(o0))[s4]            = ev4(0, vr);
    ((float4*)(o0 + HWSZ))[s4]     = ev4(1, vg);
    ((float4*)(o0 + 2 * HWSZ))[s4] = ev4(2, vb);
  }
}

// ---------------------------------------------------------------------------
extern "C" void kernel_launch(void* const* d_in, const int* in_sizes, int n_in,
                              void* d_out, int out_size, void* d_ws, size_t ws_size,
                              hipStream_t stream) {
  const float* x   = (const float*)d_in[0];
  const float* f   = (const float*)d_in[1];
  const float* bf  = (const float*)d_in[2];
  const float* pw1 = (const float*)d_in[3];
  const float* pb1 = (const float*)d_in[4];
  const float* pw2 = (const float*)d_in[5];
  const float* pb2 = (const float*)d_in[6];
  const float* fw1 = (const float*)d_in[7];
  const float* fb1 = (const float*)d_in[8];
  const float* fw2 = (const float*)d_in[9];
  const float* fb2 = (const float*)d_in[10];
  float* out = (float*)d_out;
  float* ws  = (float*)d_ws;

  dim3 grid(32, 8);
  k_fused<<<grid, 512, 0, stream>>>(x, f, bf, pw1, pb1, pw2, pb2,
                                    fw1, fb1, fw2, fb2, ws, out);
}

// Round 2
// 97.922 us; speedup vs baseline: 1.1246x; 1.1246x over previous
//
#include <hip/hip_runtime.h>

// Problem constants
#define HWSZ 65536             // 256*256
#define PLANE (3 * HWSZ)       // one batch's [3,H,W]
#define OUTSTRIDE (8 * PLANE)  // one full output tensor [8,3,256,256]
#define MAGIC 0x13572468       // != 0xAAAAAAAA ws poison

// ---------------------------------------------------------------------------
// Fused MLP: 32 blocks x 384. R12 structure, but with ONE global sync instead
// of two: fc2 is computed split-K (each block uses only its own fc1 quarter
// h[c4*48:+48], producing a rank-48 partial of all 192 outputs). The 4-way
// partial sum + fb2 bias is deferred to k_render's LUT build. Kernel-boundary
// release/acquire makes the partials visible — no B-phase flags, no hc
// round-trip through ws.
__global__ __launch_bounds__(384) void k_mlp(
    const float* __restrict__ f, const float* __restrict__ bf,
    const float* __restrict__ pw1, const float* __restrict__ pb1,
    const float* __restrict__ pw2, const float* __restrict__ pb2,
    const float* __restrict__ fw1, const float* __restrict__ fb1,
    const float* __restrict__ fw2, const float* __restrict__ fb2,
    float* __restrict__ ws) {
  __shared__ float smem[2304];
  int t = threadIdx.x, blk = blockIdx.x;

  float* outs    = ws;         // [4,8,192]
  float* partial = ws + 8192;  // [4,8,192] fc2 split-K partials
  int* fbase = (int*)(ws + 16384);
  // flagA[i] = fbase[i*16] (i<32)

  // ======== Phase A: proj for (k,b) ========
  int k = blk >> 3, b = blk & 7;
  {
    int q = t % 48, s = t / 48;  // s in 0..7
    float* sf  = smem;           // 512
    float* red = smem + 512;     // 8*192
    float* sh  = smem + 2048;    // 192

    const float* feat = ((k & 1) ? bf : f) + b * 512;
    for (int i = t; i < 512; i += 384) sf[i] = feat[i];
    __syncthreads();

    {  // 512 -> 192
      const float4* w = (const float4*)(pw1 + (size_t)k * (512 * 192));
      float4 acc = {0.f, 0.f, 0.f, 0.f};
      int i0 = s * 64;
      for (int r = 0; r < 4; ++r) {
        float4 wv[16];
#pragma unroll
        for (int j = 0; j < 16; ++j)
          wv[j] = w[(size_t)(i0 + r * 16 + j) * 48 + q];
#pragma unroll
        for (int j = 0; j < 16; ++j) {
          float v = sf[i0 + r * 16 + j];
          acc.x = fmaf(v, wv[j].x, acc.x); acc.y = fmaf(v, wv[j].y, acc.y);
          acc.z = fmaf(v, wv[j].z, acc.z); acc.w = fmaf(v, wv[j].w, acc.w);
        }
      }
      ((float4*)(red + s * 192))[q] = acc;
    }
    __syncthreads();
    if (t < 192) {
      float a = pb1[k * 192 + t];
#pragma unroll
      for (int s2 = 0; s2 < 8; ++s2) a += red[s2 * 192 + t];
      sh[t] = fmaxf(a, 0.f);
    }
    __syncthreads();
    {  // 192 -> 192
      const float4* w = (const float4*)(pw2 + (size_t)k * (192 * 192));
      float4 acc = {0.f, 0.f, 0.f, 0.f};
      int i0 = s * 24;
      for (int r = 0; r < 2; ++r) {
        float4 wv[12];
#pragma unroll
        for (int j = 0; j < 12; ++j)
          wv[j] = w[(size_t)(i0 + r * 12 + j) * 48 + q];
#pragma unroll
        for (int j = 0; j < 12; ++j) {
          float v = sh[i0 + r * 12 + j];
          acc.x = fmaf(v, wv[j].x, acc.x); acc.y = fmaf(v, wv[j].y, acc.y);
          acc.z = fmaf(v, wv[j].z, acc.z); acc.w = fmaf(v, wv[j].w, acc.w);
        }
      }
      ((float4*)(red + s * 192))[q] = acc;
    }
    __syncthreads();
    if (t < 192) {
      float a = pb2[k * 192 + t];
#pragma unroll
      for (int s2 = 0; s2 < 8; ++s2) a += red[s2 * 192 + t];
      outs[(k * 8 + b) * 192 + t] = a;
    }
    __syncthreads();  // drain stores before fence
    if (t == 0) {
      __threadfence();
      atomicExch(&fbase[blk * 16], MAGIC);
    }
  }

  // ======== Phase B: fc1 quarter + local split-K fc2 (NO second sync) ====
  int b2 = blk & 7, c4 = blk >> 3, ob2 = c4 * 48;
  int q = t % 12, s = t / 12;    // s in 0..31 (fc1 layout)
  int q2 = t % 48, s2 = t / 48;  // s2 in 0..7 (fc2 split-K layout)

  // prefetch fw1 slice AND fw2 rows (both independent of outs) BEFORE spin
  float4 wv1[18];
  {
    const float4* w = (const float4*)fw1;
    int i0 = s * 18;
#pragma unroll
    for (int j = 0; j < 18; ++j)
      wv1[j] = w[(size_t)(i0 + j) * 48 + (ob2 >> 2) + q];
  }
  float4 wv2[6];
  {
    // fw2 rows ob2 + s2*6 + j (this block's h quarter), all 192 cols via q2
    const float4* w = (const float4*)fw2;
#pragma unroll
    for (int j = 0; j < 6; ++j)
      wv2[j] = w[(size_t)(ob2 + s2 * 6 + j) * 48 + q2];
  }

  if (t < 4) {
    while (atomicAdd(&fbase[(t * 8 + b2) * 16], 0) != MAGIC)
      __builtin_amdgcn_s_sleep(2);
  }
  __syncthreads();
  if (t == 0) __threadfence();  // acquire
  __syncthreads();

  {
    float* sc  = smem;           // 576 (cat input)
    float* red = smem + 576;     // 32*48 (fc1 reduce)
    for (int idx = t; idx < 576; idx += 384) {
      float v;
      if (idx < 192)      v = outs[(0 * 8 + b2) * 192 + idx];
      else if (idx < 384) v = outs[(1 * 8 + b2) * 192 + (idx - 192)];
      else                v = outs[(2 * 8 + b2) * 192 + (idx - 384)] +
                              outs[(3 * 8 + b2) * 192 + (idx - 384)];
      sc[idx] = v;
    }
    __syncthreads();
    {  // fc1: 576 -> 48 (this block's output quarter)
      float4 acc = {0.f, 0.f, 0.f, 0.f};
      int i0 = s * 18;
#pragma unroll
      for (int j = 0; j < 18; ++j) {
        float v = sc[i0 + j];
        acc.x = fmaf(v, wv1[j].x, acc.x); acc.y = fmaf(v, wv1[j].y, acc.y);
        acc.z = fmaf(v, wv1[j].z, acc.z); acc.w = fmaf(v, wv1[j].w, acc.w);
      }
      ((float4*)(red + s * 48))[q] = acc;
    }
    __syncthreads();
    if (t < 48) {  // h quarter -> smem[0..47] (sc area dead now)
      float a = fb1[ob2 + t];
#pragma unroll
      for (int s3 = 0; s3 < 32; ++s3) a += red[s3 * 48 + t];
      smem[t] = fmaxf(a, 0.f);
    }
    __syncthreads();
    {  // fc2 split-K: partial[j] = sum_{i in quarter} h[i]*fw2[i][j]
      float4 acc = {0.f, 0.f, 0.f, 0.f};
#pragma unroll
      for (int j = 0; j < 6; ++j) {
        float v = smem[s2 * 6 + j];
        acc.x = fmaf(v, wv2[j].x, acc.x); acc.y = fmaf(v, wv2[j].y, acc.y);
        acc.z = fmaf(v, wv2[j].z, acc.z); acc.w = fmaf(v, wv2[j].w, acc.w);
      }
      ((float4*)(red + s2 * 192))[q2] = acc;  // red reads all done (sync'd)
    }
    __syncthreads();
    if (t < 192) {
      float a = (c4 == 0) ? fb2[t] : 0.f;  // bias added exactly once
#pragma unroll
      for (int s3 = 0; s3 < 8; ++s3) a += red[s3 * 192 + t];
      partial[(c4 * 8 + b2) * 192 + t] = a;
    }
    // no fence/flag: kernel-boundary release + stream order covers k_render
  }
}

// ---------------------------------------------------------------------------
// Render: 256 blocks (32,8) x 256 threads, 2 float4 per thread per channel.
// LUT entry e[k] = {S_k*norm/64, p_k*norm}. Gray curves share k/tt.
// Curves 0..2 (full param) sum the 4 fc2 split-K partials inline.
__global__ __launch_bounds__(256) void k_render(
    const float* __restrict__ x, const float* __restrict__ ws,
    float* __restrict__ out) {
  int b = blockIdx.y, t = threadIdx.x;
  int wave = t >> 6, lane = t & 63;
  const float* outs    = ws;
  const float* partial = ws + 8192;
  __shared__ float2 tab[576];

  // prefetch both x float4 groups
  int s4a = blockIdx.x * 512 + t, s4b = s4a + 256;
  const float* xb = x + (size_t)b * PLANE;
  float4 vr0 = ((const float4*)(xb))[s4a];
  float4 vr1 = ((const float4*)(xb))[s4b];
  float4 vg0 = ((const float4*)(xb + HWSZ))[s4a];
  float4 vg1 = ((const float4*)(xb + HWSZ))[s4b];
  float4 vb0 = ((const float4*)(xb + 2 * HWSZ))[s4a];
  float4 vb1 = ((const float4*)(xb + 2 * HWSZ))[s4b];

  for (int cur = wave; cur < 9; cur += 4) {
    int oi = cur / 3, c = cur - oi * 3;
    float p;
    if (oi == 0) {
      const float* pp = partial + b * 192 + c * 64;
      p = pp[lane] + pp[1536 + lane] + pp[3072 + lane] + pp[4608 + lane];
    } else {
      p = outs[((oi - 1) * 8 + b) * 192 + c * 64 + lane];
    }
    float v = p;  // inclusive scan
#pragma unroll
    for (int d = 1; d < 64; d <<= 1) {
      float n = __shfl_up(v, d, 64);
      if (lane >= d) v += n;
    }
    float total = __shfl(v, 63, 64);
    float norm = 64.f / (total + 1e-30f);
    tab[cur * 64 + lane] = make_float2((v - p) * 0.015625f * norm, p * norm);
  }
  __syncthreads();

  auto idx_of = [&](float v, int& kk, float& tt) {
    int k = (int)(v * 64.f);
    k = k < 0 ? 0 : (k > 63 ? 63 : k);
    kk = k;
    tt = v - (float)k * 0.015625f;
  };
  auto evk = [&](int cur, int k, float tt) -> float {
    float2 e = tab[cur * 64 + k];
    return fmaf(tt, e.y, e.x);
  };
  auto ev4 = [&](int cur, float4 v) -> float4 {
    int k; float tt; float4 r;
    idx_of(v.x, k, tt); r.x = evk(cur, k, tt);
    idx_of(v.y, k, tt); r.y = evk(cur, k, tt);
    idx_of(v.z, k, tt); r.z = evk(cur, k, tt);
    idx_of(v.w, k, tt); r.w = evk(cur, k, tt);
    return r;
  };

  float* o0 = out + (size_t)b * PLANE;
  float* o1 = out + OUTSTRIDE + (size_t)b * PLANE;
  float* o2 = out + 2 * OUTSTRIDE + (size_t)b * PLANE;

  auto process = [&](int s4, float4 vr, float4 vg, float4 vb) {
    float4 gr;
    gr.x = fmaf(0.299f, vr.x, fmaf(0.587f, vg.x, 0.114f * vb.x));
    gr.y = fmaf(0.299f, vr.y, fmaf(0.587f, vg.y, 0.114f * vb.y));
    gr.z = fmaf(0.299f, vr.z, fmaf(0.587f, vg.z, 0.114f * vb.z));
    gr.w = fmaf(0.299f, vr.w, fmaf(0.587f, vg.w, 0.114f * vb.w));

    ((float4*)(o0))[s4]            = ev4(0, vr);
    ((float4*)(o0 + HWSZ))[s4]     = ev4(1, vg);
    ((float4*)(o0 + 2 * HWSZ))[s4] = ev4(2, vb);

    // gray: shared piece index across curves 3..8
    int kx, ky, kz, kw; float tx, ty, tz, tw;
    idx_of(gr.x, kx, tx); idx_of(gr.y, ky, ty);
    idx_of(gr.z, kz, tz); idx_of(gr.w, kw, tw);
#pragma unroll
    for (int c = 0; c < 3; ++c) {
      float4 r;
      r.x = evk(3 + c, kx, tx); r.y = evk(3 + c, ky, ty);
      r.z = evk(3 + c, kz, tz); r.w = evk(3 + c, kw, tw);
      ((float4*)(o1 + c * HWSZ))[s4] = r;
    }
#pragma unroll
    for (int c = 0; c < 3; ++c) {
      float4 r;
      r.x = evk(6 + c, kx, tx); r.y = evk(6 + c, ky, ty);
      r.z = evk(6 + c, kz, tz); r.w = evk(6 + c, kw, tw);
      ((float4*)(o2 + c * HWSZ))[s4] = r;
    }
  };

  process(s4a, vr0, vg0, vb0);
  process(s4b, vr1, vg1, vb1);
}

// ---------------------------------------------------------------------------
extern "C" void kernel_launch(void* const* d_in, const int* in_sizes, int n_in,
                              void* d_out, int out_size, void* d_ws, size_t ws_size,
                              hipStream_t stream) {
  const float* x   = (const float*)d_in[0];
  const float* f   = (const float*)d_in[1];
  const float* bf  = (const float*)d_in[2];
  const float* pw1 = (const float*)d_in[3];
  const float* pb1 = (const float*)d_in[4];
  const float* pw2 = (const float*)d_in[5];
  const float* pb2 = (const float*)d_in[6];
  const float* fw1 = (const float*)d_in[7];
  const float* fb1 = (const float*)d_in[8];
  const float* fw2 = (const float*)d_in[9];
  const float* fb2 = (const float*)d_in[10];
  float* out = (float*)d_out;
  float* ws  = (float*)d_ws;

  k_mlp<<<32, 384, 0, stream>>>(f, bf, pw1, pb1, pw2, pb2, fw1, fb1, fw2,
                                fb2, ws);
  dim3 grid(32, 8);
  k_render<<<grid, 256, 0, stream>>>(x, ws, out);
}

// Round 4
// 95.232 us; speedup vs baseline: 1.1564x; 1.0283x over previous
//
#include <hip/hip_runtime.h>

// Problem constants
#define HWSZ 65536             // 256*256
#define PLANE (3 * HWSZ)       // one batch's [3,H,W]
#define OUTSTRIDE (8 * PLANE)  // one full output tensor [8,3,256,256]
#define MAGIC 0x13572468       // != 0xAAAAAAAA ws poison

// ws layout (floats):
//   pA      = ws + 0       [4][8][2][192]  layer-2 split-K partials (no pb2)
//   partial = ws + 12288   [4][8][192]     fc2 split-K partials (fb2 in c4==0)
//   fbase   = (int*)(ws + 20480), flag i at fbase[i*16], i = b*8 + slice
//
// 64 phase-A blocks: blk = b*8 + s, s = k*2 + half. XCD(blk)=blk%8=s, so all
// 8 batch-sharers of one weight slice sit on ONE XCD -> slice is HBM-fetched
// once per XCD, re-served from L2. Per-block weight bytes halved vs 32-block
// layout (196KB pw1-half + 73KB pw2-rows), still exactly ONE global sync.
__global__ __launch_bounds__(384) void k_mlp(
    const float* __restrict__ f, const float* __restrict__ bf,
    const float* __restrict__ pw1, const float* __restrict__ pb1,
    const float* __restrict__ pw2, const float* __restrict__ pb2,
    const float* __restrict__ fw1, const float* __restrict__ fb1,
    const float* __restrict__ fw2, const float* __restrict__ fb2,
    float* __restrict__ ws) {
  __shared__ float smem[2304];
  int t = threadIdx.x, blk = blockIdx.x;

  float* pA      = ws;          // [4,8,2,192]
  float* partial = ws + 12288;  // [4,8,192]
  int* fbase = (int*)(ws + 20480);

  // ======== Phase A: layer1 output-half + layer2 split-K for (k,b,half) ===
  int s = blk & 7, b = blk >> 3;
  int k = s >> 1, half = s & 1, o0 = half * 96;
  {
    float* sf  = smem;           // 512
    float* red = smem + 512;     // 16*96 (then 8*192)
    float* sh  = smem + 2048;    // 96 (own h half)

    const float* feat = ((k & 1) ? bf : f) + b * 512;
    for (int i = t; i < 512; i += 384) sf[i] = feat[i];
    __syncthreads();

    {  // layer1: 512 -> 96 (cols o0..o0+95)
      int q = t % 24, sr = t / 24;  // sr in 0..15, 32 rows each
      const float4* w = (const float4*)(pw1 + (size_t)k * (512 * 192));
      int icol = half * 24 + q;
      float4 acc = {0.f, 0.f, 0.f, 0.f};
      int i0 = sr * 32;
      for (int r = 0; r < 2; ++r) {
        float4 wv[16];
#pragma unroll
        for (int j = 0; j < 16; ++j)
          wv[j] = w[(size_t)(i0 + r * 16 + j) * 48 + icol];
#pragma unroll
        for (int j = 0; j < 16; ++j) {
          float v = sf[i0 + r * 16 + j];
          acc.x = fmaf(v, wv[j].x, acc.x); acc.y = fmaf(v, wv[j].y, acc.y);
          acc.z = fmaf(v, wv[j].z, acc.z); acc.w = fmaf(v, wv[j].w, acc.w);
        }
      }
      ((float4*)(red + sr * 96))[q] = acc;
    }
    __syncthreads();
    if (t < 96) {
      float a = pb1[k * 192 + o0 + t];
#pragma unroll
      for (int s2 = 0; s2 < 16; ++s2) a += red[s2 * 96 + t];
      sh[t] = fmaxf(a, 0.f);
    }
    __syncthreads();
    {  // layer2 split-K: own 96 h-rows x all 192 cols -> pA partial
      int q2 = t % 48, s2 = t / 48;  // s2 in 0..7, 12 rows each
      const float4* w = (const float4*)(pw2 + (size_t)k * (192 * 192));
      float4 acc = {0.f, 0.f, 0.f, 0.f};
      float4 wv[12];
#pragma unroll
      for (int j = 0; j < 12; ++j)
        wv[j] = w[(size_t)(o0 + s2 * 12 + j) * 48 + q2];
#pragma unroll
      for (int j = 0; j < 12; ++j) {
        float v = sh[s2 * 12 + j];
        acc.x = fmaf(v, wv[j].x, acc.x); acc.y = fmaf(v, wv[j].y, acc.y);
        acc.z = fmaf(v, wv[j].z, acc.z); acc.w = fmaf(v, wv[j].w, acc.w);
      }
      ((float4*)(red + s2 * 192))[q2] = acc;
    }
    __syncthreads();
    if (t < 192) {
      float a = 0.f;  // pb2 added by consumers (once per (k,b) sum)
#pragma unroll
      for (int s3 = 0; s3 < 8; ++s3) a += red[s3 * 192 + t];
      pA[((k * 8 + b) * 2 + half) * 192 + t] = a;
    }
    __syncthreads();  // drain stores before fence
    if (t == 0) {
      __threadfence();
      atomicExch(&fbase[blk * 16], MAGIC);
    }
  }

  if (s >= 4) return;  // blocks 4..7 per b: phase A only

  // ======== Phase B: fc1 quarter + local split-K fc2 (blocks s<4) ========
  int b2 = b, c4 = s, ob2 = c4 * 48;
  int q = t % 12, sb = t / 12;   // sb in 0..31 (fc1 layout)
  int q2 = t % 48, s2 = t / 48;  // s2 in 0..7 (fc2 split-K layout)

  // prefetch fw1 slice AND fw2 rows (independent of pA) BEFORE the spin
  float4 wv1[18];
  {
    const float4* w = (const float4*)fw1;
    int i0 = sb * 18;
#pragma unroll
    for (int j = 0; j < 18; ++j)
      wv1[j] = w[(size_t)(i0 + j) * 48 + c4 * 12 + q];
  }
  float4 wv2[6];
  {
    const float4* w = (const float4*)fw2;
#pragma unroll
    for (int j = 0; j < 6; ++j)
      wv2[j] = w[(size_t)(ob2 + s2 * 6 + j) * 48 + q2];
  }

  if (t < 8) {  // need all 8 slices of this b
    while (atomicAdd(&fbase[((b2 << 3) + t) * 16], 0) != MAGIC)
      __builtin_amdgcn_s_sleep(2);
  }
  __syncthreads();
  if (t == 0) __threadfence();  // acquire
  __syncthreads();

  {
    float* sc  = smem;           // 576 (cat input)
    float* red = smem + 576;     // 32*48 (fc1 reduce)
    for (int idx = t; idx < 576; idx += 384) {
      float v;
      if (idx < 192) {
        const float* p0 = pA + ((0 * 8 + b2) * 2) * 192;
        v = p0[idx] + p0[192 + idx] + pb2[idx];
      } else if (idx < 384) {
        int jj = idx - 192;
        const float* p1 = pA + ((1 * 8 + b2) * 2) * 192;
        v = p1[jj] + p1[192 + jj] + pb2[192 + jj];
      } else {
        int jj = idx - 384;
        const float* p2 = pA + ((2 * 8 + b2) * 2) * 192;
        const float* p3 = pA + ((3 * 8 + b2) * 2) * 192;
        v = p2[jj] + p2[192 + jj] + p3[jj] + p3[192 + jj] +
            pb2[384 + jj] + pb2[576 + jj];
      }
      sc[idx] = v;
    }
    __syncthreads();
    {  // fc1: 576 -> 48 (this block's output quarter)
      float4 acc = {0.f, 0.f, 0.f, 0.f};
      int i0 = sb * 18;
#pragma unroll
      for (int j = 0; j < 18; ++j) {
        float v = sc[i0 + j];
        acc.x = fmaf(v, wv1[j].x, acc.x); acc.y = fmaf(v, wv1[j].y, acc.y);
        acc.z = fmaf(v, wv1[j].z, acc.z); acc.w = fmaf(v, wv1[j].w, acc.w);
      }
      ((float4*)(red + sb * 48))[q] = acc;
    }
    __syncthreads();
    if (t < 48) {  // h quarter -> smem[0..47] (sc area dead now)
      float a = fb1[ob2 + t];
#pragma unroll
      for (int s3 = 0; s3 < 32; ++s3) a += red[s3 * 48 + t];
      smem[t] = fmaxf(a, 0.f);
    }
    __syncthreads();
    {  // fc2 split-K: partial[j] = sum_{i in quarter} h[i]*fw2[i][j]
      float4 acc = {0.f, 0.f, 0.f, 0.f};
#pragma unroll
      for (int j = 0; j < 6; ++j) {
        float v = smem[s2 * 6 + j];
        acc.x = fmaf(v, wv2[j].x, acc.x); acc.y = fmaf(v, wv2[j].y, acc.y);
        acc.z = fmaf(v, wv2[j].z, acc.z); acc.w = fmaf(v, wv2[j].w, acc.w);
      }
      ((float4*)(red + s2 * 192))[q2] = acc;
    }
    __syncthreads();
    if (t < 192) {
      float a = (c4 == 0) ? fb2[t] : 0.f;  // bias added exactly once
#pragma unroll
      for (int s3 = 0; s3 < 8; ++s3) a += red[s3 * 192 + t];
      partial[(c4 * 8 + b2) * 192 + t] = a;
    }
    // no fence/flag: kernel-boundary release + stream order covers k_render
  }
}

// ---------------------------------------------------------------------------
// Render: 256 blocks (32,8) x 256 threads, 2 float4 per thread per channel.
// LUT entry e[k] = {S_k*norm/64, p_k*norm}. Gray curves share k/tt.
// Curves 0..2 sum the 4 fc2 partials; curves 3..8 sum the 2 pA halves + pb2.
__global__ __launch_bounds__(256) void k_render(
    const float* __restrict__ x, const float* __restrict__ ws,
    const float* __restrict__ pb2, float* __restrict__ out) {
  int b = blockIdx.y, t = threadIdx.x;
  int wave = t >> 6, lane = t & 63;
  const float* pA      = ws;
  const float* partial = ws + 12288;
  __shared__ float2 tab[576];

  // prefetch both x float4 groups
  int s4a = blockIdx.x * 512 + t, s4b = s4a + 256;
  const float* xb = x + (size_t)b * PLANE;
  float4 vr0 = ((const float4*)(xb))[s4a];
  float4 vr1 = ((const float4*)(xb))[s4b];
  float4 vg0 = ((const float4*)(xb + HWSZ))[s4a];
  float4 vg1 = ((const float4*)(xb + HWSZ))[s4b];
  float4 vb0 = ((const float4*)(xb + 2 * HWSZ))[s4a];
  float4 vb1 = ((const float4*)(xb + 2 * HWSZ))[s4b];

  for (int cur = wave; cur < 9; cur += 4) {
    int oi = cur / 3, c = cur - oi * 3;
    float p;
    if (oi == 0) {
      const float* pp = partial + b * 192 + c * 64;
      p = pp[lane] + pp[1536 + lane] + pp[3072 + lane] + pp[4608 + lane];
    } else {
      const float* pa = pA + (((oi - 1) * 8 + b) * 2) * 192 + c * 64;
      p = pa[lane] + pa[192 + lane] + pb2[(oi - 1) * 192 + c * 64 + lane];
    }
    float v = p;  // inclusive scan
#pragma unroll
    for (int d = 1; d < 64; d <<= 1) {
      float n = __shfl_up(v, d, 64);
      if (lane >= d) v += n;
    }
    float total = __shfl(v, 63, 64);
    float norm = 64.f / (total + 1e-30f);
    tab[cur * 64 + lane] = make_float2((v - p) * 0.015625f * norm, p * norm);
  }
  __syncthreads();

  auto idx_of = [&](float v, int& kk, float& tt) {
    int k = (int)(v * 64.f);
    k = k < 0 ? 0 : (k > 63 ? 63 : k);
    kk = k;
    tt = v - (float)k * 0.015625f;
  };
  auto evk = [&](int cur, int k, float tt) -> float {
    float2 e = tab[cur * 64 + k];
    return fmaf(tt, e.y, e.x);
  };
  auto ev4 = [&](int cur, float4 v) -> float4 {
    int k; float tt; float4 r;
    idx_of(v.x, k, tt); r.x = evk(cur, k, tt);
    idx_of(v.y, k, tt); r.y = evk(cur, k, tt);
    idx_of(v.z, k, tt); r.z = evk(cur, k, tt);
    idx_of(v.w, k, tt); r.w = evk(cur, k, tt);
    return r;
  };

  float* o0 = out + (size_t)b * PLANE;
  float* o1 = out + OUTSTRIDE + (size_t)b * PLANE;
  float* o2 = out + 2 * OUTSTRIDE + (size_t)b * PLANE;

  auto process = [&](int s4, float4 vr, float4 vg, float4 vb) {
    float4 gr;
    gr.x = fmaf(0.299f, vr.x, fmaf(0.587f, vg.x, 0.114f * vb.x));
    gr.y = fmaf(0.299f, vr.y, fmaf(0.587f, vg.y, 0.114f * vb.y));
    gr.z = fmaf(0.299f, vr.z, fmaf(0.587f, vg.z, 0.114f * vb.z));
    gr.w = fmaf(0.299f, vr.w, fmaf(0.587f, vg.w, 0.114f * vb.w));

    ((float4*)(o0))[s4]            = ev4(0, vr);
    ((float4*)(o0 + HWSZ))[s4]     = ev4(1, vg);
    ((float4*)(o0 + 2 * HWSZ))[s4] = ev4(2, vb);

    // gray: shared piece index across curves 3..8
    int kx, ky, kz, kw; float tx, ty, tz, tw;
    idx_of(gr.x, kx, tx); idx_of(gr.y, ky, ty);
    idx_of(gr.z, kz, tz); idx_of(gr.w, kw, tw);
#pragma unroll
    for (int c = 0; c < 3; ++c) {
      float4 r;
      r.x = evk(3 + c, kx, tx); r.y = evk(3 + c, ky, ty);
      r.z = evk(3 + c, kz, tz); r.w = evk(3 + c, kw, tw);
      ((float4*)(o1 + c * HWSZ))[s4] = r;
    }
#pragma unroll
    for (int c = 0; c < 3; ++c) {
      float4 r;
      r.x = evk(6 + c, kx, tx); r.y = evk(6 + c, ky, ty);
      r.z = evk(6 + c, kz, tz); r.w = evk(6 + c, kw, tw);
      ((float4*)(o2 + c * HWSZ))[s4] = r;
    }
  };

  process(s4a, vr0, vg0, vb0);
  process(s4b, vr1, vg1, vb1);
}

// ---------------------------------------------------------------------------
extern "C" void kernel_launch(void* const* d_in, const int* in_sizes, int n_in,
                              void* d_out, int out_size, void* d_ws, size_t ws_size,
                              hipStream_t stream) {
  const float* x   = (const float*)d_in[0];
  const float* f   = (const float*)d_in[1];
  const float* bf  = (const float*)d_in[2];
  const float* pw1 = (const float*)d_in[3];
  const float* pb1 = (const float*)d_in[4];
  const float* pw2 = (const float*)d_in[5];
  const float* pb2 = (const float*)d_in[6];
  const float* fw1 = (const float*)d_in[7];
  const float* fb1 = (const float*)d_in[8];
  const float* fw2 = (const float*)d_in[9];
  const float* fb2 = (const float*)d_in[10];
  float* out = (float*)d_out;
  float* ws  = (float*)d_ws;

  k_mlp<<<64, 384, 0, stream>>>(f, bf, pw1, pb1, pw2, pb2, fw1, fb1, fw2,
                                fb2, ws);
  dim3 grid(32, 8);
  k_render<<<grid, 256, 0, stream>>>(x, ws, pb2, out);
}